// Round 1
// baseline (201.104 us; speedup 1.0000x reference)
//
#include <hip/hip_runtime.h>

// FeynNet: out[b,o,p] = relu( bn2( conv(bn1( max(gather(feat_a,assign_a),
//                                              gather(feat_b,assign_b)) )) ) )
// B=128, C=32, N=12, P=8192, M=2. Output (B,C,P) fp32 = 134 MB -> write-bound.
//
// Strategy:
//  - fold_kernel (1 block): fold bn1+bn2 into W''[o][c] = W[o][c]*s1[c]*s2[o]
//    and bias''[o] = s2[o]*sum_c W[o][c]*t1[c] + t2[o], into d_ws.
//  - main_kernel: 1 thread = 1 (b,p) position; feat for batch b staged in LDS
//    TRANSPOSED (fa[n][c], padded stride) so each gather source is 8x
//    ds_read_b128; x[32] lives in VGPRs; W''/bias'' read with wave-uniform
//    addresses -> s_load (scalar pipe), inner loop is pure v_fmac_f32.

#define EPS 1e-5f
constexpr int B  = 128;
constexpr int C  = 32;
constexpr int NA = 12;
constexpr int PP = 8192;   // P
constexpr int PT = 256;    // positions per block
constexpr int FS = 36;     // padded transposed-feat row stride (36*4=144 B, 16B aligned)

__global__ __launch_bounds__(256) void fold_kernel(
    const float* __restrict__ conv_w,
    const float* __restrict__ g1, const float* __restrict__ b1,
    const float* __restrict__ m1, const float* __restrict__ v1,
    const float* __restrict__ g2, const float* __restrict__ b2,
    const float* __restrict__ m2, const float* __restrict__ v2,
    float* __restrict__ wpp, float* __restrict__ bpp)
{
    __shared__ float s1[C], t1[C], s2[C], t2[C];
    int tid = threadIdx.x;
    if (tid < C) {
        float s = g1[tid] * rsqrtf(v1[tid] + EPS);
        s1[tid] = s;
        t1[tid] = b1[tid] - m1[tid] * s;
        float ss = g2[tid] * rsqrtf(v2[tid] + EPS);
        s2[tid] = ss;
        t2[tid] = b2[tid] - m2[tid] * ss;
    }
    __syncthreads();
    for (int i = tid; i < C * C; i += 256) {
        int o = i >> 5, c = i & 31;
        wpp[i] = conv_w[i] * s1[c] * s2[o];
    }
    if (tid < C) {
        float acc = 0.f;
        for (int c = 0; c < C; ++c) acc += conv_w[tid * C + c] * t1[c];
        bpp[tid] = acc * s2[tid] + t2[tid];
    }
}

__global__ __launch_bounds__(256) void main_kernel(
    const float* __restrict__ feat_a, const float* __restrict__ feat_b,
    const int*   __restrict__ assign_a, const int* __restrict__ assign_b,
    const float* __restrict__ wpp, const float* __restrict__ bpp,
    float* __restrict__ out)
{
    __shared__ float fa[NA * FS];
    __shared__ float fb[NA * FS];

    const int tid = threadIdx.x;
    const int b  = blockIdx.x >> 5;      // PP/PT = 32 tiles per batch
    const int p0 = (blockIdx.x & 31) * PT;

    // Stage feat for this batch, transposed: fa[n*FS + c] = feat_a[b][c][n].
    // Coalesced global reads; LDS write bank skew via FS=36 (4-bank stride).
    for (int i = tid; i < C * NA; i += 256) {
        int c = i / NA, n = i - c * NA;
        fa[n * FS + c] = feat_a[b * C * NA + i];
        fb[n * FS + c] = feat_b[b * C * NA + i];
    }
    __syncthreads();

    const int p = p0 + tid;
    const int2 ia = ((const int2*)assign_a)[p];   // assign_a[p][0], [p][1]
    const int2 ib = ((const int2*)assign_b)[p];

    const float* ra0 = &fa[ia.x * FS];
    const float* ra1 = &fa[ia.y * FS];
    const float* rb0 = &fb[ib.x * FS];
    const float* rb1 = &fb[ib.y * FS];

    // Gather + max over 4 sources, vectorized: 4 x 8 ds_read_b128.
    float x[C];
#pragma unroll
    for (int cc = 0; cc < C; cc += 4) {
        float4 va0 = *(const float4*)(ra0 + cc);
        float4 va1 = *(const float4*)(ra1 + cc);
        float4 vb0 = *(const float4*)(rb0 + cc);
        float4 vb1 = *(const float4*)(rb1 + cc);
        x[cc + 0] = fmaxf(fmaxf(va0.x, va1.x), fmaxf(vb0.x, vb1.x));
        x[cc + 1] = fmaxf(fmaxf(va0.y, va1.y), fmaxf(vb0.y, vb1.y));
        x[cc + 2] = fmaxf(fmaxf(va0.z, va1.z), fmaxf(vb0.z, vb1.z));
        x[cc + 3] = fmaxf(fmaxf(va0.w, va1.w), fmaxf(vb0.w, vb1.w));
    }

    // 32x32 matvec; wpp/bpp indices are wave-uniform -> scalar loads.
    float* outp = out + b * C * PP + p;
#pragma unroll 4
    for (int o = 0; o < C; ++o) {
        float acc = bpp[o];
#pragma unroll
        for (int c = 0; c < C; ++c)
            acc = fmaf(wpp[o * C + c], x[c], acc);
        outp[o * PP] = fmaxf(acc, 0.f);
    }
}

extern "C" void kernel_launch(void* const* d_in, const int* in_sizes, int n_in,
                              void* d_out, int out_size, void* d_ws, size_t ws_size,
                              hipStream_t stream) {
    const float* feat_a   = (const float*)d_in[0];
    const float* feat_b   = (const float*)d_in[1];
    const int*   assign_a = (const int*)  d_in[2];
    const int*   assign_b = (const int*)  d_in[3];
    const float* g1 = (const float*)d_in[4];
    const float* b1 = (const float*)d_in[5];
    const float* m1 = (const float*)d_in[6];
    const float* v1 = (const float*)d_in[7];
    const float* cw = (const float*)d_in[8];
    const float* g2 = (const float*)d_in[9];
    const float* b2 = (const float*)d_in[10];
    const float* m2 = (const float*)d_in[11];
    const float* v2 = (const float*)d_in[12];

    float* out = (float*)d_out;
    float* wpp = (float*)d_ws;          // 1024 floats
    float* bpp = wpp + C * C;           // 32 floats

    fold_kernel<<<1, 256, 0, stream>>>(cw, g1, b1, m1, v1, g2, b2, m2, v2, wpp, bpp);
    main_kernel<<<B * (PP / PT), 256, 0, stream>>>(feat_a, feat_b, assign_a, assign_b,
                                                   wpp, bpp, out);
}

// Round 2
// 175.849 us; speedup vs baseline: 1.1436x; 1.1436x over previous
//
#include <hip/hip_runtime.h>

// FeynNet: out[b,o,p] = relu( bn2( conv(bn1( max(gather(feat_a,assign_a),
//                                              gather(feat_b,assign_b)) )) ) )
// B=128, C=32, N=12, P=8192, M=2. Output (B,C,P) fp32 = 134 MB -> write-bound
// floor ~21 us; fp32 FMA work ~14 us.
//
// R2 change: R1 read W''/bias'' from GLOBAL in the inner loop, trusting LLVM
// to emit s_load. 201 us says it didn't (1056 VMEM/thread ~ 110+ us of VMEM
// issue). Now W''+bias'' are staged in LDS: wave-uniform LDS reads are
// hardware broadcasts (conflict-free), guaranteed off the VMEM pipe.
// Also 2 positions/thread to amortize the W broadcast reads.

#define EPS 1e-5f
constexpr int B  = 128;
constexpr int C  = 32;
constexpr int NA = 12;
constexpr int PP = 8192;   // P
constexpr int PT = 512;    // positions per block (256 threads x 2)
constexpr int FS = 36;     // padded transposed-feat row stride (144 B: 16B-aligned, 4-bank skew)

__global__ __launch_bounds__(256) void fold_kernel(
    const float* __restrict__ conv_w,
    const float* __restrict__ g1, const float* __restrict__ b1,
    const float* __restrict__ m1, const float* __restrict__ v1,
    const float* __restrict__ g2, const float* __restrict__ b2,
    const float* __restrict__ m2, const float* __restrict__ v2,
    float* __restrict__ wpp, float* __restrict__ bpp)
{
    __shared__ float s1[C], t1[C], s2[C], t2[C];
    int tid = threadIdx.x;
    if (tid < C) {
        float s = g1[tid] * rsqrtf(v1[tid] + EPS);
        s1[tid] = s;
        t1[tid] = b1[tid] - m1[tid] * s;
        float ss = g2[tid] * rsqrtf(v2[tid] + EPS);
        s2[tid] = ss;
        t2[tid] = b2[tid] - m2[tid] * ss;
    }
    __syncthreads();
    for (int i = tid; i < C * C; i += 256) {
        int o = i >> 5, c = i & 31;
        wpp[i] = conv_w[i] * s1[c] * s2[o];
    }
    if (tid < C) {
        float acc = 0.f;
        for (int c = 0; c < C; ++c) acc += conv_w[tid * C + c] * t1[c];
        bpp[tid] = acc * s2[tid] + t2[tid];
    }
}

__global__ __launch_bounds__(256, 4) void main_kernel(
    const float* __restrict__ feat_a, const float* __restrict__ feat_b,
    const int*   __restrict__ assign_a, const int* __restrict__ assign_b,
    const float* __restrict__ wpp, const float* __restrict__ bpp,
    float* __restrict__ out)
{
    __shared__ float fa[NA * FS];
    __shared__ float fb[NA * FS];
    __shared__ float wsh[C * C];
    __shared__ float bsh[C];

    const int tid = threadIdx.x;
    const int b  = blockIdx.x >> 4;      // PP/PT = 16 tiles per batch
    const int p0 = (blockIdx.x & 15) * PT;

    // Stage W''(1024) + bias''(32) into LDS; broadcast reads in the hot loop.
    for (int i = tid; i < C * C; i += 256) wsh[i] = wpp[i];
    if (tid < C) bsh[tid] = bpp[tid];

    // Stage feat for this batch, transposed: fa[n*FS + c] = feat_a[b][c][n].
    for (int i = tid; i < C * NA; i += 256) {
        int c = i / NA, n = i - c * NA;
        fa[n * FS + c] = feat_a[b * C * NA + i];
        fb[n * FS + c] = feat_b[b * C * NA + i];
    }
    __syncthreads();

    const int pA = p0 + tid;
    const int pB = pA + 256;
    const int2 ia0 = ((const int2*)assign_a)[pA];
    const int2 ib0 = ((const int2*)assign_b)[pA];
    const int2 ia1 = ((const int2*)assign_a)[pB];
    const int2 ib1 = ((const int2*)assign_b)[pB];

    // Gather + 4-way max for both positions. fa rows: at worst 2-way bank
    // conflicts (free on gfx950).
    float x0[C], x1[C];
    {
        const float* a0 = &fa[ia0.x * FS];
        const float* a1 = &fa[ia0.y * FS];
        const float* b0 = &fb[ib0.x * FS];
        const float* b1 = &fb[ib0.y * FS];
        const float* a2 = &fa[ia1.x * FS];
        const float* a3 = &fa[ia1.y * FS];
        const float* b2 = &fb[ib1.x * FS];
        const float* b3 = &fb[ib1.y * FS];
#pragma unroll
        for (int cc = 0; cc < C; cc += 4) {
            float4 va0 = *(const float4*)(a0 + cc);
            float4 va1 = *(const float4*)(a1 + cc);
            float4 vb0 = *(const float4*)(b0 + cc);
            float4 vb1 = *(const float4*)(b1 + cc);
            x0[cc + 0] = fmaxf(fmaxf(va0.x, va1.x), fmaxf(vb0.x, vb1.x));
            x0[cc + 1] = fmaxf(fmaxf(va0.y, va1.y), fmaxf(vb0.y, vb1.y));
            x0[cc + 2] = fmaxf(fmaxf(va0.z, va1.z), fmaxf(vb0.z, vb1.z));
            x0[cc + 3] = fmaxf(fmaxf(va0.w, va1.w), fmaxf(vb0.w, vb1.w));
            float4 wa0 = *(const float4*)(a2 + cc);
            float4 wa1 = *(const float4*)(a3 + cc);
            float4 wb0 = *(const float4*)(b2 + cc);
            float4 wb1 = *(const float4*)(b3 + cc);
            x1[cc + 0] = fmaxf(fmaxf(wa0.x, wa1.x), fmaxf(wb0.x, wb1.x));
            x1[cc + 1] = fmaxf(fmaxf(wa0.y, wa1.y), fmaxf(wb0.y, wb1.y));
            x1[cc + 2] = fmaxf(fmaxf(wa0.z, wa1.z), fmaxf(wb0.z, wb1.z));
            x1[cc + 3] = fmaxf(fmaxf(wa0.w, wa1.w), fmaxf(wb0.w, wb1.w));
        }
    }

    // 32x32 matvec for 2 positions; W row via LDS broadcast (amortized 2x).
    float* out0 = out + b * C * PP + pA;
    float* out1 = out + b * C * PP + pB;
#pragma unroll 2
    for (int o = 0; o < C; ++o) {
        const float* wr = &wsh[o * C];
        float acc0 = bsh[o];
        float acc1 = acc0;
#pragma unroll
        for (int c = 0; c < C; c += 4) {
            float4 w = *(const float4*)(wr + c);
            acc0 = fmaf(w.x, x0[c + 0], acc0);
            acc1 = fmaf(w.x, x1[c + 0], acc1);
            acc0 = fmaf(w.y, x0[c + 1], acc0);
            acc1 = fmaf(w.y, x1[c + 1], acc1);
            acc0 = fmaf(w.z, x0[c + 2], acc0);
            acc1 = fmaf(w.z, x1[c + 2], acc1);
            acc0 = fmaf(w.w, x0[c + 3], acc0);
            acc1 = fmaf(w.w, x1[c + 3], acc1);
        }
        out0[o * PP] = fmaxf(acc0, 0.f);
        out1[o * PP] = fmaxf(acc1, 0.f);
    }
}

extern "C" void kernel_launch(void* const* d_in, const int* in_sizes, int n_in,
                              void* d_out, int out_size, void* d_ws, size_t ws_size,
                              hipStream_t stream) {
    const float* feat_a   = (const float*)d_in[0];
    const float* feat_b   = (const float*)d_in[1];
    const int*   assign_a = (const int*)  d_in[2];
    const int*   assign_b = (const int*)  d_in[3];
    const float* g1 = (const float*)d_in[4];
    const float* b1 = (const float*)d_in[5];
    const float* m1 = (const float*)d_in[6];
    const float* v1 = (const float*)d_in[7];
    const float* cw = (const float*)d_in[8];
    const float* g2 = (const float*)d_in[9];
    const float* b2 = (const float*)d_in[10];
    const float* m2 = (const float*)d_in[11];
    const float* v2 = (const float*)d_in[12];

    float* out = (float*)d_out;
    float* wpp = (float*)d_ws;          // 1024 floats
    float* bpp = wpp + C * C;           // 32 floats

    fold_kernel<<<1, 256, 0, stream>>>(cw, g1, b1, m1, v1, g2, b2, m2, v2, wpp, bpp);
    main_kernel<<<B * (PP / PT), 256, 0, stream>>>(feat_a, feat_b, assign_a, assign_b,
                                                   wpp, bpp, out);
}

// Round 3
// 174.456 us; speedup vs baseline: 1.1527x; 1.0080x over previous
//
#include <hip/hip_runtime.h>

// FeynNet: out[b,o,p] = relu(bn2(conv(bn1(max(gather_a, gather_b)))))
// B=128, C=32, N=12, P=8192, M=2. Output 134 MB fp32 -> write floor ~21 us.
//
// R3: replace the VALU matvec (whose per-position W broadcast reads made the
// per-CU LDS pipe the bottleneck: 320 ds_read_b128/wave per 128 positions)
// with MFMA. A-operand = BN-folded W'' held in VGPRs for the whole kernel
// (zero recurring W cost). Precision: hi/lo bf16 split of both W'' and x,
// 3 MFMAs per o-tile (wh*xh + wh*xl + wl*xh) -> ~1e-3 added error vs 0.1075
// threshold. Layouts (HW-verified m89/m120): A[m=lane&15][k=(lane>>4)*8+j],
// B[k=(lane>>4)*8+j][n=lane&15], D: col=lane&15, row=(lane>>4)*4+reg.

#define EPS 1e-5f
constexpr int B  = 128;
constexpr int C  = 32;
constexpr int NA = 12;
constexpr int PP = 8192;   // P
constexpr int PT = 256;    // positions per block (1 per thread in phase 1)
constexpr int FS = 36;     // fa/fb row stride (floats): 144 B, 16B-aligned
constexpr int XS = 40;     // x row stride (ushorts): 80 B, 16B-aligned

typedef short bfv8  __attribute__((ext_vector_type(8)));   // 8 bf16 = 4 VGPRs
typedef float f32x4 __attribute__((ext_vector_type(4)));

__device__ __forceinline__ ushort f2bf(float f) {          // RNE fp32->bf16
    uint u = __float_as_uint(f);
    u += 0x7fffu + ((u >> 16) & 1u);
    return (ushort)(u >> 16);
}
__device__ __forceinline__ float bf2f(ushort h) {
    return __uint_as_float(((uint)h) << 16);
}
__device__ __forceinline__ uint pk(ushort lo, ushort hi) {
    return (uint)lo | ((uint)hi << 16);
}

// Fold bn1+bn2 into W''[o][c], split into bf16 hi/lo A-fragments (frag order:
// [tile][lane][j]), plus fp32 bias''[o].
__global__ __launch_bounds__(256) void fold_kernel(
    const float* __restrict__ conv_w,
    const float* __restrict__ g1, const float* __restrict__ b1,
    const float* __restrict__ m1, const float* __restrict__ v1,
    const float* __restrict__ g2, const float* __restrict__ b2,
    const float* __restrict__ m2, const float* __restrict__ v2,
    ushort* __restrict__ afh, ushort* __restrict__ afl,
    float* __restrict__ bpp)
{
    __shared__ float s1[C], t1[C], s2[C], t2[C], w2[C * C];
    int tid = threadIdx.x;
    if (tid < C) {
        float s = g1[tid] * rsqrtf(v1[tid] + EPS);
        s1[tid] = s;
        t1[tid] = b1[tid] - m1[tid] * s;
        float ss = g2[tid] * rsqrtf(v2[tid] + EPS);
        s2[tid] = ss;
        t2[tid] = b2[tid] - m2[tid] * ss;
    }
    __syncthreads();
    for (int i = tid; i < C * C; i += 256) {
        int o = i >> 5, c = i & 31;
        w2[i] = conv_w[i] * s1[c] * s2[o];
    }
    if (tid < C) {
        float acc = 0.f;
        for (int c = 0; c < C; ++c) acc += conv_w[tid * C + c] * t1[c];
        bpp[tid] = acc * s2[tid] + t2[tid];
    }
    __syncthreads();
    // 1024 fragment entries: e = tile*512 + lane*8 + j
#pragma unroll
    for (int e = tid * 4; e < tid * 4 + 4; ++e) {
        int t = e >> 9, l = (e >> 3) & 63, j = e & 7;
        int m = (l & 15) + 16 * t;        // output row o
        int k = (l >> 4) * 8 + j;         // input channel c
        float w = w2[m * C + k];
        ushort h = f2bf(w);
        afh[e] = h;
        afl[e] = f2bf(w - bf2f(h));
    }
}

__global__ __launch_bounds__(256) void main_kernel(
    const float* __restrict__ feat_a, const float* __restrict__ feat_b,
    const int*   __restrict__ assign_a, const int* __restrict__ assign_b,
    const ushort* __restrict__ afh, const ushort* __restrict__ afl,
    const float* __restrict__ bpp,
    float* __restrict__ out)
{
    __shared__ __align__(16) float  fa[NA * FS];
    __shared__ __align__(16) float  fb[NA * FS];
    __shared__ __align__(16) ushort xh[PT * XS];
    __shared__ __align__(16) ushort xl[PT * XS];

    const int tid  = threadIdx.x;
    const int lane = tid & 63;
    const int b    = blockIdx.x >> 5;          // 32 tiles per batch
    const int p0   = (blockIdx.x & 31) * PT;
    const int q    = lane >> 4;                // k-quad / row-quad
    const int n    = lane & 15;                // position within 16-chunk

    // A fragments (held in VGPRs all kernel) + per-lane bias values.
    bfv8 ah0 = *(const bfv8*)(afh + lane * 8);
    bfv8 ah1 = *(const bfv8*)(afh + 512 + lane * 8);
    bfv8 al0 = *(const bfv8*)(afl + lane * 8);
    bfv8 al1 = *(const bfv8*)(afl + 512 + lane * 8);
    float bias0[4], bias1[4];
#pragma unroll
    for (int r = 0; r < 4; ++r) {
        bias0[r] = bpp[q * 4 + r];
        bias1[r] = bpp[16 + q * 4 + r];
    }

    // Stage feat transposed: fa[nn*FS + c] = feat_a[b][c][nn].
    for (int i = tid; i < C * NA; i += 256) {
        int c = i / NA, nn = i - c * NA;
        fa[nn * FS + c] = feat_a[b * C * NA + i];
        fb[nn * FS + c] = feat_b[b * C * NA + i];
    }
    __syncthreads();

    // ---- Phase 1: gather+max (fp32), split to bf16 hi/lo, write to LDS ----
    {
        const int p = p0 + tid;
        const int2 ia = ((const int2*)assign_a)[p];
        const int2 ib = ((const int2*)assign_b)[p];
        const float* a0 = &fa[ia.x * FS];
        const float* a1 = &fa[ia.y * FS];
        const float* c0 = &fb[ib.x * FS];
        const float* c1 = &fb[ib.y * FS];

        float x[C];
#pragma unroll
        for (int cc = 0; cc < C; cc += 4) {
            float4 va0 = *(const float4*)(a0 + cc);
            float4 va1 = *(const float4*)(a1 + cc);
            float4 vb0 = *(const float4*)(c0 + cc);
            float4 vb1 = *(const float4*)(c1 + cc);
            x[cc + 0] = fmaxf(fmaxf(va0.x, va1.x), fmaxf(vb0.x, vb1.x));
            x[cc + 1] = fmaxf(fmaxf(va0.y, va1.y), fmaxf(vb0.y, vb1.y));
            x[cc + 2] = fmaxf(fmaxf(va0.z, va1.z), fmaxf(vb0.z, vb1.z));
            x[cc + 3] = fmaxf(fmaxf(va0.w, va1.w), fmaxf(vb0.w, vb1.w));
        }

        ushort* rowh = &xh[tid * XS];
        ushort* rowl = &xl[tid * XS];
#pragma unroll
        for (int c = 0; c < C; c += 8) {
            ushort h[8], l[8];
#pragma unroll
            for (int j = 0; j < 8; ++j) {
                float v = x[c + j];
                h[j] = f2bf(v);
                l[j] = f2bf(v - bf2f(h[j]));
            }
            uint4 vh = make_uint4(pk(h[0], h[1]), pk(h[2], h[3]),
                                  pk(h[4], h[5]), pk(h[6], h[7]));
            uint4 vl = make_uint4(pk(l[0], l[1]), pk(l[2], l[3]),
                                  pk(l[4], l[5]), pk(l[6], l[7]));
            *(uint4*)(rowh + c) = vh;   // byte off = tid*80 + 2c (16B-mult)
            *(uint4*)(rowl + c) = vl;
        }
    }
    __syncthreads();

    // ---- Phase 2: MFMA over 16-position chunks; wave w owns chunks [4w,4w+4) ----
    const int wave = tid >> 6;
    const f32x4 zero = {0.f, 0.f, 0.f, 0.f};
    float* outb = out + b * C * PP + p0;
#pragma unroll
    for (int ch = 0; ch < 4; ++ch) {
        const int base = (wave * 4 + ch) * 16;
        const bfv8 bh = *(const bfv8*)&xh[(base + n) * XS + q * 8];
        const bfv8 bl = *(const bfv8*)&xl[(base + n) * XS + q * 8];

        f32x4 d0 = __builtin_amdgcn_mfma_f32_16x16x32_bf16(ah0, bh, zero, 0, 0, 0);
        d0       = __builtin_amdgcn_mfma_f32_16x16x32_bf16(ah0, bl, d0,   0, 0, 0);
        d0       = __builtin_amdgcn_mfma_f32_16x16x32_bf16(al0, bh, d0,   0, 0, 0);
        f32x4 d1 = __builtin_amdgcn_mfma_f32_16x16x32_bf16(ah1, bh, zero, 0, 0, 0);
        d1       = __builtin_amdgcn_mfma_f32_16x16x32_bf16(ah1, bl, d1,   0, 0, 0);
        d1       = __builtin_amdgcn_mfma_f32_16x16x32_bf16(al1, bh, d1,   0, 0, 0);

        float* op = outb + base + n;
#pragma unroll
        for (int r = 0; r < 4; ++r) {
            op[(q * 4 + r) * PP]      = fmaxf(d0[r] + bias0[r], 0.f);
            op[(16 + q * 4 + r) * PP] = fmaxf(d1[r] + bias1[r], 0.f);
        }
    }
}

extern "C" void kernel_launch(void* const* d_in, const int* in_sizes, int n_in,
                              void* d_out, int out_size, void* d_ws, size_t ws_size,
                              hipStream_t stream) {
    const float* feat_a   = (const float*)d_in[0];
    const float* feat_b   = (const float*)d_in[1];
    const int*   assign_a = (const int*)  d_in[2];
    const int*   assign_b = (const int*)  d_in[3];
    const float* g1 = (const float*)d_in[4];
    const float* b1 = (const float*)d_in[5];
    const float* m1 = (const float*)d_in[6];
    const float* v1 = (const float*)d_in[7];
    const float* cw = (const float*)d_in[8];
    const float* g2 = (const float*)d_in[9];
    const float* b2 = (const float*)d_in[10];
    const float* m2 = (const float*)d_in[11];
    const float* v2 = (const float*)d_in[12];

    float* out = (float*)d_out;
    ushort* afh = (ushort*)d_ws;                 // 1024 ushort = 2048 B
    ushort* afl = (ushort*)((char*)d_ws + 2048); // 1024 ushort
    float*  bpp = (float*)((char*)d_ws + 4096);  // 32 floats

    fold_kernel<<<1, 256, 0, stream>>>(cw, g1, b1, m1, v1, g2, b2, m2, v2,
                                       afh, afl, bpp);
    main_kernel<<<B * (PP / PT), 256, 0, stream>>>(feat_a, feat_b,
                                                   assign_a, assign_b,
                                                   afh, afl, bpp, out);
}

// Round 4
// 170.999 us; speedup vs baseline: 1.1761x; 1.0202x over previous
//
#include <hip/hip_runtime.h>

// FeynNet: out[b,o,p] = relu(bn2(conv(bn1(max(gather_a, gather_b)))))
// B=128, C=32, N=12, P=8192, M=2. Output 134 MB fp32 -> write floor ~21 us.
//
// R4: single fused kernel (fold merged; serial 1-block fold dispatch removed).
// MFMA path: A = BN-folded W'' as bf16 hi/lo fragments in VGPRs (W error
// ~2^-17, negligible); x = single bf16 (RNE is monotone so bf16(max) ==
// max(bf16); only x rounding ~2^-8 rel enters -> absmax ~0.03 vs 0.1075
// threshold). Per 16-pos chunk: 1 ds_read_b128 (B-frag) + 4 MFMA + 8 stores.
// LDS de-conflict: w2 stride 36 (2-way max = free), xh rows swizzled in
// 16B groups (slot = (q + r + (r>>3)) & 3) to break 8-way conflicts from
// the 80 B row stride.

#define EPS 1e-5f
constexpr int B   = 128;
constexpr int C   = 32;
constexpr int NA  = 12;
constexpr int PP  = 8192;  // P
constexpr int PT  = 256;   // positions per block
constexpr int FS  = 36;    // fa/fb row stride (floats): 144 B
constexpr int XS  = 40;    // xh row stride (ushorts): 80 B
constexpr int W2S = 36;    // w2 row stride (floats): 144 B, 16B-aligned

typedef short bfv8  __attribute__((ext_vector_type(8)));   // 8 bf16 = 4 VGPRs
typedef float f32x4 __attribute__((ext_vector_type(4)));

__device__ __forceinline__ ushort f2bf(float f) {          // RNE fp32->bf16
    uint u = __float_as_uint(f);
    u += 0x7fffu + ((u >> 16) & 1u);
    return (ushort)(u >> 16);
}
__device__ __forceinline__ float bf2f(ushort h) {
    return __uint_as_float(((uint)h) << 16);
}
__device__ __forceinline__ uint pk(ushort lo, ushort hi) {
    return (uint)lo | ((uint)hi << 16);
}

__global__ __launch_bounds__(256) void main_kernel(
    const float* __restrict__ feat_a, const float* __restrict__ feat_b,
    const int*   __restrict__ assign_a, const int* __restrict__ assign_b,
    const float* __restrict__ conv_w,
    const float* __restrict__ g1, const float* __restrict__ b1,
    const float* __restrict__ m1, const float* __restrict__ v1,
    const float* __restrict__ g2, const float* __restrict__ b2,
    const float* __restrict__ m2, const float* __restrict__ v2,
    float* __restrict__ out)
{
    __shared__ float s1[C], t1[C], s2v[C], bsh[C];
    __shared__ __align__(16) float  w2[C * W2S];
    __shared__ __align__(16) float  fa[NA * FS];
    __shared__ __align__(16) float  fb[NA * FS];
    __shared__ __align__(16) ushort xh[PT * XS];

    const int tid  = threadIdx.x;
    const int lane = tid & 63;
    const int b    = blockIdx.x >> 5;          // 32 position-tiles per batch
    const int p0   = (blockIdx.x & 31) * PT;
    const int q    = lane >> 4;                // k-quad / row-quad
    const int n    = lane & 15;                // position within 16-chunk

    // ---- Fold stage 1: BN scales + feat staging (independent) ----
    if (tid < C) {
        float s = g1[tid] * rsqrtf(v1[tid] + EPS);
        s1[tid]  = s;
        t1[tid]  = b1[tid] - m1[tid] * s;
        s2v[tid] = g2[tid] * rsqrtf(v2[tid] + EPS);
    }
    for (int i = tid; i < C * NA; i += 256) {   // fa[nn*FS+c] = feat[b][c][nn]
        int c = i / NA, nn = i - c * NA;
        fa[nn * FS + c] = feat_a[b * C * NA + i];
        fb[nn * FS + c] = feat_b[b * C * NA + i];
    }
    __syncthreads();

    // ---- Fold stage 2: W''[o][c] (fp32, LDS) + bias''[o] ----
    for (int i = tid; i < C * C; i += 256) {
        int o = i >> 5, c = i & 31;
        w2[o * W2S + c] = conv_w[i] * s1[c] * s2v[o];
    }
    if (tid < C) {
        float acc = 0.f;
        for (int c = 0; c < C; ++c) acc += conv_w[tid * C + c] * t1[c];
        bsh[tid] = acc * s2v[tid] + (b2[tid] - m2[tid] * s2v[tid]);
    }
    __syncthreads();

    // ---- A-fragments (bf16 hi/lo) into VGPRs; bias into VGPRs ----
    // A[m][k]: m = (lane&15)+16*tile, k = q*8+j  (verified layout, R3 passed)
    bfv8 ah0, al0, ah1, al1;
    {
        float wv0[8], wv1[8];
        const float* r0 = &w2[(lane & 15) * W2S + q * 8];
        const float* r1 = &w2[((lane & 15) + 16) * W2S + q * 8];
        *(float4*)&wv0[0] = *(const float4*)(r0);
        *(float4*)&wv0[4] = *(const float4*)(r0 + 4);
        *(float4*)&wv1[0] = *(const float4*)(r1);
        *(float4*)&wv1[4] = *(const float4*)(r1 + 4);
#pragma unroll
        for (int j = 0; j < 8; ++j) {
            ushort h0 = f2bf(wv0[j]);
            ah0[j] = (short)h0;
            al0[j] = (short)f2bf(wv0[j] - bf2f(h0));
            ushort h1 = f2bf(wv1[j]);
            ah1[j] = (short)h1;
            al1[j] = (short)f2bf(wv1[j] - bf2f(h1));
        }
    }
    float bias0[4], bias1[4];
#pragma unroll
    for (int r = 0; r < 4; ++r) {
        bias0[r] = bsh[q * 4 + r];
        bias1[r] = bsh[16 + q * 4 + r];
    }

    // ---- Phase 1: gather + 4-way max (fp32), bf16-pack, swizzled LDS ----
    {
        const int p = p0 + tid;
        const int2 ia = ((const int2*)assign_a)[p];
        const int2 ib = ((const int2*)assign_b)[p];
        const float* a0 = &fa[ia.x * FS];
        const float* a1 = &fa[ia.y * FS];
        const float* c0 = &fb[ib.x * FS];
        const float* c1 = &fb[ib.y * FS];

        float x[C];
#pragma unroll
        for (int cc = 0; cc < C; cc += 4) {
            float4 va0 = *(const float4*)(a0 + cc);
            float4 va1 = *(const float4*)(a1 + cc);
            float4 vb0 = *(const float4*)(c0 + cc);
            float4 vb1 = *(const float4*)(c1 + cc);
            x[cc + 0] = fmaxf(fmaxf(va0.x, va1.x), fmaxf(vb0.x, vb1.x));
            x[cc + 1] = fmaxf(fmaxf(va0.y, va1.y), fmaxf(vb0.y, vb1.y));
            x[cc + 2] = fmaxf(fmaxf(va0.z, va1.z), fmaxf(vb0.z, vb1.z));
            x[cc + 3] = fmaxf(fmaxf(va0.w, va1.w), fmaxf(vb0.w, vb1.w));
        }

        ushort* rowh = &xh[tid * XS];
        const int rot = (tid + (tid >> 3)) & 3;
#pragma unroll
        for (int g = 0; g < 4; ++g) {
            const int c = g * 8;
            ushort h[8];
#pragma unroll
            for (int j = 0; j < 8; ++j) h[j] = f2bf(x[c + j]);
            uint4 vh = make_uint4(pk(h[0], h[1]), pk(h[2], h[3]),
                                  pk(h[4], h[5]), pk(h[6], h[7]));
            *(uint4*)(rowh + ((g + rot) & 3) * 8) = vh;
        }
    }
    __syncthreads();

    // ---- Phase 2: MFMA; wave w owns 16-pos chunks [4w, 4w+4) ----
    const int wave = tid >> 6;
    const f32x4 zero = {0.f, 0.f, 0.f, 0.f};
    float* outb = out + b * C * PP + p0;
#pragma unroll
    for (int ch = 0; ch < 4; ++ch) {
        const int base = (wave * 4 + ch) * 16;
        const int r    = base + n;
        const int slot = (q + r + (r >> 3)) & 3;
        const bfv8 bh  = *(const bfv8*)&xh[r * XS + slot * 8];

        f32x4 d0 = __builtin_amdgcn_mfma_f32_16x16x32_bf16(ah0, bh, zero, 0, 0, 0);
        d0       = __builtin_amdgcn_mfma_f32_16x16x32_bf16(al0, bh, d0,   0, 0, 0);
        f32x4 d1 = __builtin_amdgcn_mfma_f32_16x16x32_bf16(ah1, bh, zero, 0, 0, 0);
        d1       = __builtin_amdgcn_mfma_f32_16x16x32_bf16(al1, bh, d1,   0, 0, 0);

        float* op = outb + base + n;
#pragma unroll
        for (int rr = 0; rr < 4; ++rr) {
            op[(q * 4 + rr) * PP]      = fmaxf(d0[rr] + bias0[rr], 0.f);
            op[(16 + q * 4 + rr) * PP] = fmaxf(d1[rr] + bias1[rr], 0.f);
        }
    }
}

extern "C" void kernel_launch(void* const* d_in, const int* in_sizes, int n_in,
                              void* d_out, int out_size, void* d_ws, size_t ws_size,
                              hipStream_t stream) {
    const float* feat_a   = (const float*)d_in[0];
    const float* feat_b   = (const float*)d_in[1];
    const int*   assign_a = (const int*)  d_in[2];
    const int*   assign_b = (const int*)  d_in[3];
    const float* g1 = (const float*)d_in[4];
    const float* b1 = (const float*)d_in[5];
    const float* m1 = (const float*)d_in[6];
    const float* v1 = (const float*)d_in[7];
    const float* cw = (const float*)d_in[8];
    const float* g2 = (const float*)d_in[9];
    const float* b2 = (const float*)d_in[10];
    const float* m2 = (const float*)d_in[11];
    const float* v2 = (const float*)d_in[12];

    float* out = (float*)d_out;
    (void)d_ws; (void)ws_size;

    main_kernel<<<B * (PP / PT), 256, 0, stream>>>(
        feat_a, feat_b, assign_a, assign_b, cw,
        g1, b1, m1, v1, g2, b2, m2, v2, out);
}